// Round 3
// baseline (168.443 us; speedup 1.0000x reference)
//
#include <hip/hip_runtime.h>
#include <math.h>

#define B_ 4096
#define L_ 50
#define D_ 200
#define A_ 14
#define S_ 30

// ws layout (floats): anchors only
#define WS_HYP   0
#define WS_KLE   (A_ * D_)
#define WS_Y2    (2 * A_ * D_)
#define WS_LF    (WS_Y2 + A_)

// ---------- helpers ----------
__device__ __forceinline__ float wave_reduce_sum(float v) {
    #pragma unroll
    for (int off = 32; off > 0; off >>= 1) v += __shfl_down(v, off, 64);
    return v;   // valid in lane 0
}

// 8-wave block reduce; result broadcast to all threads
__device__ __forceinline__ float block_reduce_512(float val, volatile float* red) {
    __syncthreads();                 // protects red[] and prior LDS reads
    val = wave_reduce_sum(val);
    if ((threadIdx.x & 63) == 0) red[threadIdx.x >> 6] = val;
    __syncthreads();
    float s = 0.f;
    #pragma unroll
    for (int i = 0; i < 8; ++i) s += red[i];
    return s;
}

// ---------- kernel 0: anchor precompute (tiny) ----------
__global__ __launch_bounds__(256) void precompute_anchors(
    const float* __restrict__ a_emb, const float* __restrict__ seed_w,
    float* __restrict__ ws)
{
    __shared__ float u[A_][D_];
    __shared__ float nrm2[A_];
    const int t = threadIdx.x;
    const int wave = t >> 6, lane = t & 63;

    for (int d = t; d < D_; d += 256) {
        for (int a = 0; a < A_; ++a) {
            float acc = 0.f;
            #pragma unroll 5
            for (int s = 0; s < S_; ++s)
                acc += a_emb[(a * S_ + s) * D_ + d] * seed_w[a * S_ + s];
            u[a][d] = acc;
        }
    }
    __syncthreads();

    for (int a = wave; a < A_; a += 4) {
        float s = 0.f;
        for (int d = lane; d < D_; d += 64) s += u[a][d] * u[a][d];
        s = wave_reduce_sum(s);
        if (lane == 0) nrm2[a] = s;
    }
    __syncthreads();

    float* hyp = ws + WS_HYP;
    float* kle = ws + WS_KLE;
    float* y2  = ws + WS_Y2;
    float* lf  = ws + WS_LF;
    const float maxn = 1.0f - 1e-5f;

    for (int a = 0; a < A_; ++a) {
        float un = fmaxf(sqrtf(nrm2[a]), 1e-15f);
        float th = tanhf(un);
        float pn = fminf(th, maxn);
        float s  = pn / un;
        float py2 = pn * pn;
        float kscale = 2.0f / (1.0f + py2);
        float k2 = py2 * kscale * kscale;
        if (t == 0) {
            y2[a] = py2;
            lf[a] = 1.0f / sqrtf(fmaxf(1.0f - k2, 1e-7f));
        }
        for (int d = t; d < D_; d += 256) {
            float h = u[a][d] * s;
            hyp[a * D_ + d] = h;
            kle[a * D_ + d] = h * kscale;
        }
    }
}

// ---------- kernel 1: fully fused per-row pipeline (single gather) ----------
__global__ __launch_bounds__(512, 8) void fused_all(
    const int*   __restrict__ inputs,
    const float* __restrict__ emb,
    const float* __restrict__ M,
    const float* __restrict__ ws,
    float* __restrict__ out)
{
    __shared__ __align__(16) float x[L_][D_];   // 40000 B; rows reused after enc
    __shared__ __align__(16) float xavg[D_];
    __shared__ __align__(16) float v[D_];
    __shared__ float attn[L_];
    __shared__ int   sidx[L_];
    __shared__ float red[8];
    __shared__ float sums[2];

    const float* hyp = ws + WS_HYP;
    const float* kle = ws + WS_KLE;
    const float* y2  = ws + WS_Y2;
    const float* lf  = ws + WS_LF;

    const int b = blockIdx.x;
    const int t = threadIdx.x;
    const int wave = t >> 6, lane = t & 63;

    if (t < L_) sidx[t] = inputs[b * L_ + t];
    __syncthreads();

    // 1) gather x_wrd tile: flat thread-per-float4, all lanes active
    #pragma unroll
    for (int p = t; p < L_ * (D_ / 4); p += 512) {
        const int row = p / (D_ / 4);
        const int col = p % (D_ / 4);
        float4 val = ((const float4*)(emb + (size_t)sidx[row] * D_))[col];
        ((float4*)x[row])[col] = val;            // row stride 800 B, 16-aligned
    }
    __syncthreads();

    // 2) x_avg from LDS tile (conflict-free column sums)
    if (t < D_) {
        float s = 0.f;
        #pragma unroll 10
        for (int l = 0; l < L_; ++l) s += x[l][t];
        xavg[t] = s * (1.0f / (float)L_);
    }
    __syncthreads();

    // 3) v = M @ x_avg : wave per output row, float4 loads (M is L2-hot)
    for (int d = wave; d < D_; d += 8) {
        float s = 0.f;
        if (lane < D_ / 4) {
            float4 m4 = ((const float4*)(M + d * D_))[lane];
            float4 a4 = ((const float4*)xavg)[lane];
            s = m4.x * a4.x + m4.y * a4.y + m4.z * a4.z + m4.w * a4.w;
        }
        s = wave_reduce_sum(s);
        if (lane == 0) v[d] = s;
    }
    __syncthreads();

    // 4) scores: wave per l, dot(x_l, v) via float4 LDS reads
    for (int l = wave; l < L_; l += 8) {
        float s = 0.f;
        if (lane < D_ / 4) {
            float4 x4 = ((const float4*)x[l])[lane];
            float4 v4 = ((const float4*)v)[lane];
            s = x4.x * v4.x + x4.y * v4.y + x4.z * v4.z + x4.w * v4.w;
        }
        s = wave_reduce_sum(s);
        if (lane == 0) attn[l] = s;
    }
    __syncthreads();

    // 5) softmax over L (wave 0)
    if (wave == 0) {
        float scv = (lane < L_) ? attn[lane] : -INFINITY;
        float m = scv;
        #pragma unroll
        for (int off = 32; off > 0; off >>= 1) m = fmaxf(m, __shfl_xor(m, off, 64));
        float e = (lane < L_) ? expf(scv - m) : 0.f;
        float ss = e;
        #pragma unroll
        for (int off = 32; off > 0; off >>= 1) ss += __shfl_xor(ss, off, 64);
        if (lane < L_) attn[lane] = e / ss;
    }
    __syncthreads();

    // 6) enc[d]
    float encv = 0.f;
    if (t < D_) {
        #pragma unroll 10
        for (int l = 0; l < L_; ++l) encv += attn[l] * x[l][t];
    }

    // 7) expmap0 + proj
    float n2 = block_reduce_512((t < D_) ? encv * encv : 0.f, red);
    const float maxn = 1.0f - 1e-5f;
    float un = fmaxf(sqrtf(n2), 1e-15f);
    float pn = fminf(tanhf(un), maxn);
    float ps = pn / un;
    float x2 = pn * pn;
    float* pvec  = &x[0][0];          // x dead from here on
    float* dotpq = &x[1][0];
    float* pexp  = &x[1][16];
    float* pe    = &x[1][32];
    if (t < D_) pvec[t] = encv * ps;
    __syncthreads();

    // 8) dot(p, hyp_a): wave per anchor, float4
    for (int a = wave; a < A_; a += 8) {
        float s = 0.f;
        if (lane < D_ / 4) {
            float4 h4 = ((const float4*)(hyp + a * D_))[lane];
            float4 p4 = ((const float4*)pvec)[lane];
            s = h4.x * p4.x + h4.y * p4.y + h4.z * p4.z + h4.w * p4.w;
        }
        s = wave_reduce_sum(s);
        if (lane == 0) dotpq[a] = s;
    }
    __syncthreads();

    // 9) sqdist scalars -> probs_exp
    if (t < A_) {
        float dot = dotpq[t];
        float yy  = y2[t];
        float c1 = 1.0f - 2.0f * dot + yy;
        float c2 = 1.0f - x2;
        float num2 = c1 * c1 * x2 - 2.0f * c1 * c2 * dot + c2 * c2 * yy;
        float den  = fmaxf(1.0f - 2.0f * dot + x2 * yy, 1e-15f);
        float nma  = sqrtf(fmaxf(num2, 0.f)) / den;
        float z    = fminf(nma, 1.0f - 1e-7f);
        float dist = logf((1.0f + z) / (1.0f - z));
        pexp[t] = expf(-dist * dist - 0.05f);
    }
    __syncthreads();
    if (t == 0) {
        float se = 0.f, sp = 0.f;
        for (int a = 0; a < A_; ++a) { se += pexp[a]; sp += lf[a] * pexp[a]; }
        sums[0] = 1.0f / se;
        sums[1] = 1.0f / sp;
    }
    __syncthreads();
    if (t < A_) {
        float ap  = pexp[t] * sums[0];
        float pev = lf[t] * pexp[t] * sums[1];
        pe[t] = pev;
        out[B_ * D_ + b * A_ + t] = pev;                 // probs_expanded
        out[B_ * D_ + B_ * A_ + b * A_ + t] = ap;        // a_probs
    }
    __syncthreads();

    // 10) Klein barycenter -> klein_to -> logmap0
    float ko = 0.f;
    if (t < D_) {
        #pragma unroll
        for (int a = 0; a < A_; ++a) ko += kle[a * D_ + t] * pe[a];
    }
    float n2k = block_reduce_512((t < D_) ? ko * ko : 0.f, red);
    if (t < D_) {
        float denom = 1.0f + sqrtf(fmaxf(1.0f - n2k, 0.f));
        float rv = ko / denom;
        float r2 = n2k / (denom * denom);
        float rn = fmaxf(sqrtf(r2), 1e-15f);
        float z  = fminf(rn, 1.0f - 1e-7f);
        float fac = (0.5f * logf((1.0f + z) / (1.0f - z))) / rn;
        out[b * D_ + t] = fac * rv;
    }
}

extern "C" void kernel_launch(void* const* d_in, const int* in_sizes, int n_in,
                              void* d_out, int out_size, void* d_ws, size_t ws_size,
                              hipStream_t stream) {
    (void)in_sizes; (void)n_in; (void)out_size; (void)ws_size;
    const int*   inputs = (const int*)  d_in[0];
    const float* emb    = (const float*)d_in[1];
    const float* M      = (const float*)d_in[2];
    const float* a_emb  = (const float*)d_in[3];
    const float* seed_w = (const float*)d_in[4];
    float* out = (float*)d_out;
    float* ws  = (float*)d_ws;

    precompute_anchors<<<1, 256, 0, stream>>>(a_emb, seed_w, ws);
    fused_all<<<B_, 512, 0, stream>>>(inputs, emb, M, ws, out);
}

// Round 4
// 135.865 us; speedup vs baseline: 1.2398x; 1.2398x over previous
//
#include <hip/hip_runtime.h>
#include <math.h>

#define B_ 4096
#define L_ 50
#define D_ 200
#define A_ 14
#define S_ 30

// ws layout (floats)
#define WS_HYP   0
#define WS_KLE   (A_ * D_)
#define WS_Y2    (2 * A_ * D_)
#define WS_LF    (WS_Y2 + A_)
#define WS_V     8192

// ---------- helpers ----------
__device__ __forceinline__ float wave_reduce_sum(float v) {
    #pragma unroll
    for (int off = 32; off > 0; off >>= 1) v += __shfl_down(v, off, 64);
    return v;   // valid in lane 0
}

__device__ __forceinline__ float block_reduce_512(float val, volatile float* red) {
    __syncthreads();
    val = wave_reduce_sum(val);
    if ((threadIdx.x & 63) == 0) red[threadIdx.x >> 6] = val;
    __syncthreads();
    float s = 0.f;
    #pragma unroll
    for (int i = 0; i < 8; ++i) s += red[i];
    return s;
}

// ---------- kernel 0: anchor precompute (tiny) ----------
__global__ __launch_bounds__(256) void precompute_anchors(
    const float* __restrict__ a_emb, const float* __restrict__ seed_w,
    float* __restrict__ ws)
{
    __shared__ float u[A_][D_];
    __shared__ float nrm2[A_];
    const int t = threadIdx.x;
    const int wave = t >> 6, lane = t & 63;

    for (int d = t; d < D_; d += 256) {
        for (int a = 0; a < A_; ++a) {
            float acc = 0.f;
            #pragma unroll 5
            for (int s = 0; s < S_; ++s)
                acc += a_emb[(a * S_ + s) * D_ + d] * seed_w[a * S_ + s];
            u[a][d] = acc;
        }
    }
    __syncthreads();

    for (int a = wave; a < A_; a += 4) {
        float s = 0.f;
        for (int d = lane; d < D_; d += 64) s += u[a][d] * u[a][d];
        s = wave_reduce_sum(s);
        if (lane == 0) nrm2[a] = s;
    }
    __syncthreads();

    float* hyp = ws + WS_HYP;
    float* kle = ws + WS_KLE;
    float* y2  = ws + WS_Y2;
    float* lf  = ws + WS_LF;
    const float maxn = 1.0f - 1e-5f;

    for (int a = 0; a < A_; ++a) {
        float un = fmaxf(sqrtf(nrm2[a]), 1e-15f);
        float th = tanhf(un);
        float pn = fminf(th, maxn);
        float s  = pn / un;
        float py2 = pn * pn;
        float kscale = 2.0f / (1.0f + py2);
        float k2 = py2 * kscale * kscale;
        if (t == 0) {
            y2[a] = py2;
            lf[a] = 1.0f / sqrtf(fmaxf(1.0f - k2, 1e-7f));
        }
        for (int d = t; d < D_; d += 256) {
            float h = u[a][d] * s;
            hyp[a * D_ + d] = h;
            kle[a * D_ + d] = h * kscale;
        }
    }
}

// ---------- kernel 1: gather+xavg+matvec, 8 batch rows/block ----------
#define G_R 8
__global__ __launch_bounds__(512) void gather_gemm(
    const int* __restrict__ inputs, const float* __restrict__ emb,
    const float* __restrict__ M, float* __restrict__ ws)
{
    __shared__ __align__(16) float xs[G_R][D_ + 4];  // pad: r-stride 204 -> conflict-free
    __shared__ int sidx[G_R][L_];
    float* v = ws + WS_V;
    const int b0 = blockIdx.x * G_R;
    const int t = threadIdx.x;
    const int wave = t >> 6, lane = t & 63;

    for (int p = t; p < G_R * L_; p += 512) sidx[p / L_][p % L_] = inputs[b0 * L_ + p];
    __syncthreads();

    // wave `wave` gathers batch row b0+wave: 50 independent row loads, reg accumulate
    if (lane < D_ / 4) {
        float ax = 0.f, ay = 0.f, az = 0.f, aw = 0.f;
        #pragma unroll
        for (int l = 0; l < L_; ++l) {
            const float4 vv = ((const float4*)(emb + (size_t)sidx[wave][l] * D_))[lane];
            ax += vv.x; ay += vv.y; az += vv.z; aw += vv.w;
        }
        const float inv = 1.0f / (float)L_;
        ((float4*)xs[wave])[lane] = make_float4(ax * inv, ay * inv, az * inv, aw * inv);
    }
    __syncthreads();

    // matvec: thread (r = t&7, dg = t>>3); 8 batch rows share each M row (broadcast)
    const int r = t & 7, dg = t >> 3;           // dg in 0..63
    const float4* xr4 = (const float4*)xs[r];
    #pragma unroll
    for (int k = 0; k < 4; ++k) {
        const int d = dg + 64 * k;
        if (d < D_) {
            const float4* Mr4 = (const float4*)(M + d * D_);
            float acc = 0.f;
            #pragma unroll
            for (int e = 0; e < D_ / 4; ++e) {
                float4 m4 = Mr4[e], x4 = xr4[e];
                acc += m4.x * x4.x + m4.y * x4.y + m4.z * x4.z + m4.w * x4.w;
            }
            v[(size_t)(b0 + r) * D_ + d] = acc;
        }
    }
}

// ---------- kernel 2: fused per-row pipeline (single gather, v from regs) ----------
__global__ __launch_bounds__(512, 8) void fused_main(
    const int*   __restrict__ inputs,
    const float* __restrict__ emb,
    const float* __restrict__ ws,
    float* __restrict__ out)
{
    __shared__ __align__(16) float x[L_][D_];   // 40000 B; rows reused after enc
    __shared__ float attn[L_];
    __shared__ int   sidx[L_];
    __shared__ float red[8];
    __shared__ float sums[2];

    const float* hyp = ws + WS_HYP;
    const float* kle = ws + WS_KLE;
    const float* y2  = ws + WS_Y2;
    const float* lf  = ws + WS_LF;
    const float* vg  = ws + WS_V;

    const int b = blockIdx.x;
    const int t = threadIdx.x;
    const int wave = t >> 6, lane = t & 63;

    // v kept in 4 regs/lane (same mapping for every wave)
    float vr0 = vg[(size_t)b * D_ + lane];
    float vr1 = vg[(size_t)b * D_ + lane + 64];
    float vr2 = vg[(size_t)b * D_ + lane + 128];
    float vr3 = (lane < D_ - 192) ? vg[(size_t)b * D_ + lane + 192] : 0.f;

    if (t < L_) sidx[t] = inputs[b * L_ + t];
    __syncthreads();

    // 1) gather: flat thread-per-float4, 4+1 hand-unrolled batched loads
    {
        const int DQ = D_ / 4;                   // 50
        const int p0 = t, p1 = t + 512, p2 = t + 1024, p3 = t + 1536, p4 = t + 2048;
        const bool has4 = (p4 < L_ * DQ);
        float4 a0 = ((const float4*)(emb + (size_t)sidx[p0 / DQ] * D_))[p0 % DQ];
        float4 a1 = ((const float4*)(emb + (size_t)sidx[p1 / DQ] * D_))[p1 % DQ];
        float4 a2 = ((const float4*)(emb + (size_t)sidx[p2 / DQ] * D_))[p2 % DQ];
        float4 a3 = ((const float4*)(emb + (size_t)sidx[p3 / DQ] * D_))[p3 % DQ];
        float4 a4;
        if (has4) a4 = ((const float4*)(emb + (size_t)sidx[p4 / DQ] * D_))[p4 % DQ];
        ((float4*)x[p0 / DQ])[p0 % DQ] = a0;
        ((float4*)x[p1 / DQ])[p1 % DQ] = a1;
        ((float4*)x[p2 / DQ])[p2 % DQ] = a2;
        ((float4*)x[p3 / DQ])[p3 % DQ] = a3;
        if (has4) ((float4*)x[p4 / DQ])[p4 % DQ] = a4;
    }
    __syncthreads();

    // 2) scores: wave per l, dot(x_l, v)
    for (int l = wave; l < L_; l += 8) {
        float s = x[l][lane] * vr0 + x[l][lane + 64] * vr1 + x[l][lane + 128] * vr2;
        if (lane < D_ - 192) s += x[l][lane + 192] * vr3;
        s = wave_reduce_sum(s);
        if (lane == 0) attn[l] = s;
    }
    __syncthreads();

    // 3) softmax over L (wave 0)
    if (wave == 0) {
        float scv = (lane < L_) ? attn[lane] : -INFINITY;
        float m = scv;
        #pragma unroll
        for (int off = 32; off > 0; off >>= 1) m = fmaxf(m, __shfl_xor(m, off, 64));
        float e = (lane < L_) ? expf(scv - m) : 0.f;
        float ss = e;
        #pragma unroll
        for (int off = 32; off > 0; off >>= 1) ss += __shfl_xor(ss, off, 64);
        if (lane < L_) attn[lane] = e / ss;
    }
    __syncthreads();

    // 4) enc[d]
    float encv = 0.f;
    if (t < D_) {
        #pragma unroll 10
        for (int l = 0; l < L_; ++l) encv += attn[l] * x[l][t];
    }

    // 5) expmap0 + proj
    float n2 = block_reduce_512((t < D_) ? encv * encv : 0.f, red);
    const float maxn = 1.0f - 1e-5f;
    float un = fmaxf(sqrtf(n2), 1e-15f);
    float pn = fminf(tanhf(un), maxn);
    float ps = pn / un;
    float x2 = pn * pn;
    float* pvec  = &x[0][0];          // x dead from here on
    float* dotpq = &x[1][0];
    float* pexp  = &x[1][16];
    float* pe    = &x[1][32];
    if (t < D_) pvec[t] = encv * ps;
    __syncthreads();

    // 6) dot(p, hyp_a): wave per anchor
    for (int a = wave; a < A_; a += 8) {
        const float* ha = hyp + a * D_;
        float s = ha[lane] * pvec[lane] + ha[lane + 64] * pvec[lane + 64]
                + ha[lane + 128] * pvec[lane + 128];
        if (lane < D_ - 192) s += ha[lane + 192] * pvec[lane + 192];
        s = wave_reduce_sum(s);
        if (lane == 0) dotpq[a] = s;
    }
    __syncthreads();

    // 7) sqdist scalars -> probs_exp
    if (t < A_) {
        float dot = dotpq[t];
        float yy  = y2[t];
        float c1 = 1.0f - 2.0f * dot + yy;
        float c2 = 1.0f - x2;
        float num2 = c1 * c1 * x2 - 2.0f * c1 * c2 * dot + c2 * c2 * yy;
        float den  = fmaxf(1.0f - 2.0f * dot + x2 * yy, 1e-15f);
        float nma  = sqrtf(fmaxf(num2, 0.f)) / den;
        float z    = fminf(nma, 1.0f - 1e-7f);
        float dist = logf((1.0f + z) / (1.0f - z));
        pexp[t] = expf(-dist * dist - 0.05f);
    }
    __syncthreads();
    if (t == 0) {
        float se = 0.f, sp = 0.f;
        for (int a = 0; a < A_; ++a) { se += pexp[a]; sp += lf[a] * pexp[a]; }
        sums[0] = 1.0f / se;
        sums[1] = 1.0f / sp;
    }
    __syncthreads();
    if (t < A_) {
        float ap  = pexp[t] * sums[0];
        float pev = lf[t] * pexp[t] * sums[1];
        pe[t] = pev;
        out[B_ * D_ + b * A_ + t] = pev;                 // probs_expanded
        out[B_ * D_ + B_ * A_ + b * A_ + t] = ap;        // a_probs
    }
    __syncthreads();

    // 8) Klein barycenter -> klein_to -> logmap0
    float ko = 0.f;
    if (t < D_) {
        #pragma unroll
        for (int a = 0; a < A_; ++a) ko += kle[a * D_ + t] * pe[a];
    }
    float n2k = block_reduce_512((t < D_) ? ko * ko : 0.f, red);
    if (t < D_) {
        float denom = 1.0f + sqrtf(fmaxf(1.0f - n2k, 0.f));
        float rv = ko / denom;
        float r2 = n2k / (denom * denom);
        float rn = fmaxf(sqrtf(r2), 1e-15f);
        float z  = fminf(rn, 1.0f - 1e-7f);
        float fac = (0.5f * logf((1.0f + z) / (1.0f - z))) / rn;
        out[b * D_ + t] = fac * rv;
    }
}

extern "C" void kernel_launch(void* const* d_in, const int* in_sizes, int n_in,
                              void* d_out, int out_size, void* d_ws, size_t ws_size,
                              hipStream_t stream) {
    (void)in_sizes; (void)n_in; (void)out_size; (void)ws_size;
    const int*   inputs = (const int*)  d_in[0];
    const float* emb    = (const float*)d_in[1];
    const float* M      = (const float*)d_in[2];
    const float* a_emb  = (const float*)d_in[3];
    const float* seed_w = (const float*)d_in[4];
    float* out = (float*)d_out;
    float* ws  = (float*)d_ws;

    precompute_anchors<<<1, 256, 0, stream>>>(a_emb, seed_w, ws);
    gather_gemm<<<B_ / G_R, 512, 0, stream>>>(inputs, emb, M, ws);
    fused_main<<<B_, 512, 0, stream>>>(inputs, emb, ws, out);
}